// Round 1
// baseline (316.890 us; speedup 1.0000x reference)
//
#include <hip/hip_runtime.h>

#define DIMX 512
#define HEADSX 4
#define DHX 128
#define CHX 16
#define NCX 128
#define SX 2048
#define BX 2
#define BHX 8
#define PADX 520   // xs LDS row pad (ushorts): banks (4c + kk/2) -> worst 2-way (free)
#define PADF 136   // factor LDS row pad (ushorts): same property
#define NSEG 8     // scan segments
#define SEGL 16    // chunks per segment

typedef unsigned short ushort_t;
typedef unsigned int uint_t;
typedef short bf16x8 __attribute__((ext_vector_type(8)));
typedef float f32x4 __attribute__((ext_vector_type(4)));

__device__ __forceinline__ float sigmoidf_(float z){ return 1.0f/(1.0f + __expf(-z)); }

// fp32 -> bf16 round-to-nearest-even
__device__ __forceinline__ ushort_t f2bf(float f){
  uint_t u = __float_as_uint(f);
  return (ushort_t)((u + 0x7FFFu + ((u >> 16) & 1u)) >> 16);
}
__device__ __forceinline__ uint_t pk2(float a, float b){
  return (uint_t)f2bf(a) | ((uint_t)f2bf(b) << 16);
}

#define AS1 __attribute__((address_space(1)))
#define AS3 __attribute__((address_space(3)))
__device__ __forceinline__ void gl_lds16(const void* g, void* l){
#if __has_builtin(__builtin_amdgcn_global_load_lds)
  __builtin_amdgcn_global_load_lds((const AS1 void*)g, (AS3 void*)l, 16, 0, 0);
#else
  *(uint4*)l = *(const uint4*)g;
#endif
}

// ---------------- K1: RMSNorm + per-token adaptive lr ----------------
__global__ __launch_bounds__(256) void k_rms_lr(const float* __restrict__ seq,
    const float* __restrict__ scale, const float* __restrict__ Wstep,
    float* __restrict__ x, float* __restrict__ lrArr){
  int tok = blockIdx.x; int tid = threadIdx.x;
  const float* row = seq + (size_t)tok*DIMX;
  float v0 = row[tid], v1 = row[tid+256];
  float ss = v0*v0 + v1*v1;
  #pragma unroll
  for (int o=32;o>0;o>>=1) ss += __shfl_down(ss,o,64);
  __shared__ float red[4];
  __shared__ float rs_s;
  int wv = tid>>6, ln = tid&63;
  if (ln==0) red[wv]=ss;
  __syncthreads();
  if (tid==0){
    float ms = (red[0]+red[1]+red[2]+red[3]) * (1.0f/DIMX);
    rs_s = 1.0f/sqrtf(ms + 1e-6f);
  }
  __syncthreads();
  float rs = rs_s;
  float x0 = v0*rs*scale[tid];
  float x1 = v1*rs*scale[tid+256];
  size_t xo = (size_t)tok*DIMX;
  x[xo+tid]=x0; x[xo+tid+256]=x1;
  float a0 = x0*Wstep[tid*4+0] + x1*Wstep[(tid+256)*4+0];
  float a1 = x0*Wstep[tid*4+1] + x1*Wstep[(tid+256)*4+1];
  float a2 = x0*Wstep[tid*4+2] + x1*Wstep[(tid+256)*4+2];
  float a3 = x0*Wstep[tid*4+3] + x1*Wstep[(tid+256)*4+3];
  #pragma unroll
  for (int o=32;o>0;o>>=1){
    a0 += __shfl_down(a0,o,64); a1 += __shfl_down(a1,o,64);
    a2 += __shfl_down(a2,o,64); a3 += __shfl_down(a3,o,64);
  }
  __shared__ float red4[4][4];
  if (ln==0){ red4[wv][0]=a0; red4[wv][1]=a1; red4[wv][2]=a2; red4[wv][3]=a3; }
  __syncthreads();
  if (tid<4){
    float d = red4[0][tid]+red4[1][tid]+red4[2][tid]+red4[3][tid];
    int b = tok>>11, s = tok&2047;
    lrArr[(size_t)(b*HEADSX+tid)*SX + s] = 0.01f * sigmoidf_(d);
  }
}

// ---------------- K2: per-chunk mean -> mom / (1-dec) ----------------
__global__ __launch_bounds__(64) void k_stats(const float* __restrict__ x,
    const float* __restrict__ Wmom, const float* __restrict__ Wdec,
    float* __restrict__ momw, float* __restrict__ decw){
  int blk = blockIdx.x; int b = blk>>7, nc = blk&127; int ln = threadIdx.x;
  float am[4]={0,0,0,0}, ad[4]={0,0,0,0};
  const float* base = x + ((size_t)(b*SX + nc*CHX))*DIMX;
  for (int r=0;r<8;r++){
    int d = ln + 64*r;
    float m = 0.0f;
    #pragma unroll
    for (int c=0;c<CHX;c++) m += base[(size_t)c*DIMX + d];
    m *= (1.0f/CHX);
    #pragma unroll
    for (int h=0;h<4;h++){ am[h]+=m*Wmom[d*4+h]; ad[h]+=m*Wdec[d*4+h]; }
  }
  #pragma unroll
  for (int h=0;h<4;h++){
    #pragma unroll
    for (int o=32;o>0;o>>=1){ am[h]+=__shfl_down(am[h],o,64); ad[h]+=__shfl_down(ad[h],o,64); }
  }
  if (ln==0){
    #pragma unroll
    for (int h=0;h<4;h++){
      momw[(b*HEADSX+h)*NCX + nc] = sigmoidf_(am[h]);
      decw[(b*HEADSX+h)*NCX + nc] = 1.0f - sigmoidf_(ad[h]);
    }
  }
}

// ---------------- K-prep: bf16 weight layouts ----------------
__global__ __launch_bounds__(256) void k_prep(const float* __restrict__ Wkv,
    const float* __restrict__ w0, const float* __restrict__ w1,
    ushort_t* __restrict__ WkvT, ushort_t* __restrict__ w0T,
    ushort_t* __restrict__ w1T, ushort_t* __restrict__ w1n){
  int blk = blockIdx.x; int tid = threadIdx.x;
  if (blk < 64){
    int h = blk >> 4, kt = blk & 15;
    for (int i=tid; i<8192; i+=256){
      int kk = i >> 8, col = i & 255;
      int wcol = (col < 128) ? (h*128 + col) : (384 + h*128 + col);
      float v = Wkv[(size_t)(kt*32+kk)*1024 + wcol];
      WkvT[(((size_t)h*16 + kt)*256 + col)*32 + kk] = f2bf(v);
    }
  } else {
    int bh = blk - 64;
    size_t base = (size_t)bh*16384;
    for (int i=tid; i<16384; i+=256){
      int r = i >> 7, c = i & 127;
      w0T[base + i] = f2bf(w0[base + (size_t)c*128 + r]);
      w1T[base + i] = f2bf(w1[base + (size_t)c*128 + r]);
      w1n[base + i] = f2bf(w1[base + i]);
    }
  }
}

// ---------------- K-fused: kv projection + per-chunk gradient factors, all MFMA ----------------
__global__ __launch_bounds__(256) void k_fused(const float* __restrict__ x,
    const ushort_t* __restrict__ WkvT, const ushort_t* __restrict__ w0T,
    const ushort_t* __restrict__ w1T, const ushort_t* __restrict__ w1n,
    const float* __restrict__ lrArr,
    ushort_t* __restrict__ fac0, ushort_t* __restrict__ fac1){
  int blk = blockIdx.x;
  int bh = blk & 7, t = blk >> 3;
  int b = bh >> 2, h = bh & 3;
  int bt = bh*NCX + t;
  __shared__ __align__(16) ushort_t xs[16*PADX];
  __shared__ __align__(16) ushort_t ks[16*PADF];
  __shared__ __align__(16) ushort_t as_[16*PADF];
  __shared__ __align__(16) ushort_t dp_[16*PADF];
  __shared__ __align__(16) ushort_t dh_[16*PADF];
  int tid = threadIdx.x;
  int wv = tid>>6, lane = tid&63;
  int quad = lane>>4, nl = lane&15;
  const f32x4 zero = {0.f,0.f,0.f,0.f};

  const float* xb = x + ((size_t)(b*SX + t*CHX))*DIMX;
  #pragma unroll
  for (int it=0; it<8; it++){
    int f = tid + 256*it;
    int c = f >> 7, k4 = f & 127;
    float4 q = ((const float4*)xb)[(size_t)c*128 + k4];
    uint2 u; u.x = pk2(q.x,q.y); u.y = pk2(q.z,q.w);
    *(uint2*)&xs[c*PADX + k4*4] = u;
  }
  __syncthreads();

  // ---- KV gemm: M=16 (c), N=256 (k|v cols), K=512
  f32x4 kacc[2] = {zero, zero};
  f32x4 vacc[2] = {zero, zero};
  const ushort_t* wkvh = WkvT + (size_t)h*16*256*32;
  for (int kt=0; kt<16; kt++){
    bf16x8 Af = *(const bf16x8*)&xs[nl*PADX + kt*32 + quad*8];
    #pragma unroll
    for (int s=0; s<2; s++){
      int ktile = 2*wv + s;
      bf16x8 Bk = *(const bf16x8*)&wkvh[((size_t)kt*256 + (ktile*16+nl))*32 + quad*8];
      kacc[s] = __builtin_amdgcn_mfma_f32_16x16x32_bf16(Af, Bk, kacc[s], 0,0,0);
      int vtile = 8 + 2*wv + s;
      bf16x8 Bv = *(const bf16x8*)&wkvh[((size_t)kt*256 + (vtile*16+nl))*32 + quad*8];
      vacc[s] = __builtin_amdgcn_mfma_f32_16x16x32_bf16(Af, Bv, vacc[s], 0,0,0);
    }
  }
  #pragma unroll
  for (int s=0;s<2;s++){
    #pragma unroll
    for (int r=0;r<4;r++)
      ks[(quad*4+r)*PADF + 32*wv + 16*s + nl] = f2bf(kacc[s][r]);
  }
  __syncthreads();

  // ---- gemm1: h = k @ w0
  const ushort_t* w0b = w0T + (size_t)bh*16384;
  f32x4 hacc[2] = {zero, zero};
  for (int kt=0; kt<4; kt++){
    bf16x8 Af = *(const bf16x8*)&ks[nl*PADF + kt*32 + quad*8];
    #pragma unroll
    for (int s=0; s<2; s++){
      int n0 = (2*wv+s)*16;
      bf16x8 Bf = *(const bf16x8*)&w0b[(size_t)(n0+nl)*128 + kt*32 + quad*8];
      hacc[s] = __builtin_amdgcn_mfma_f32_16x16x32_bf16(Af, Bf, hacc[s], 0,0,0);
    }
  }
  float sp[2][4];
  #pragma unroll
  for (int s=0;s<2;s++){
    #pragma unroll
    for (int r=0;r<4;r++){
      float hh = hacc[s][r];
      float sg = sigmoidf_(hh);
      float a  = hh*sg;
      sp[s][r] = sg*(1.0f + hh*(1.0f-sg));
      as_[(quad*4+r)*PADF + 32*wv + 16*s + nl] = f2bf(a);
    }
  }
  __syncthreads();

  // ---- gemm2: pred = a @ w1 ; dpred = 2/DH * lr * (pred - v)
  const ushort_t* w1tb = w1T + (size_t)bh*16384;
  f32x4 pacc[2] = {zero, zero};
  for (int kt=0; kt<4; kt++){
    bf16x8 Af = *(const bf16x8*)&as_[nl*PADF + kt*32 + quad*8];
    #pragma unroll
    for (int s=0; s<2; s++){
      int n0 = (2*wv+s)*16;
      bf16x8 Bf = *(const bf16x8*)&w1tb[(size_t)(n0+nl)*128 + kt*32 + quad*8];
      pacc[s] = __builtin_amdgcn_mfma_f32_16x16x32_bf16(Af, Bf, pacc[s], 0,0,0);
    }
  }
  float lrv[4];
  #pragma unroll
  for (int r=0;r<4;r++) lrv[r] = lrArr[(size_t)bh*SX + t*CHX + quad*4 + r];
  #pragma unroll
  for (int s=0;s<2;s++){
    #pragma unroll
    for (int r=0;r<4;r++){
      float dp = (2.0f/DHX)*lrv[r]*(pacc[s][r] - vacc[s][r]);
      dp_[(quad*4+r)*PADF + 32*wv + 16*s + nl] = f2bf(dp);
    }
  }
  __syncthreads();

  // ---- gemm3: da = dpred @ w1^T ; dh0 = da * silu'(h)
  const ushort_t* w1nb = w1n + (size_t)bh*16384;
  f32x4 dacc[2] = {zero, zero};
  for (int kt=0; kt<4; kt++){
    bf16x8 Af = *(const bf16x8*)&dp_[nl*PADF + kt*32 + quad*8];
    #pragma unroll
    for (int s=0; s<2; s++){
      int n0 = (2*wv+s)*16;
      bf16x8 Bf = *(const bf16x8*)&w1nb[(size_t)(n0+nl)*128 + kt*32 + quad*8];
      dacc[s] = __builtin_amdgcn_mfma_f32_16x16x32_bf16(Af, Bf, dacc[s], 0,0,0);
    }
  }
  #pragma unroll
  for (int s=0;s<2;s++){
    #pragma unroll
    for (int r=0;r<4;r++)
      dh_[(quad*4+r)*PADF + 32*wv + 16*s + nl] = f2bf(dacc[s][r]*sp[s][r]);
  }
  __syncthreads();

  // ---- pack
  {
    int p = tid & 127, which = tid >> 7;
    const ushort_t* s0 = which ? dh_ : ks;
    const ushort_t* s1 = which ? dp_ : as_;
    ushort_t rowv[32];
    #pragma unroll
    for (int c=0;c<16;c++){ rowv[c] = s0[c*PADF + p]; rowv[16+c] = s1[c*PADF + p]; }
    ushort_t* dst = (which ? fac1 : fac0) + ((size_t)bt*128 + p)*32;
    const uint4* rv = (const uint4*)rowv;
    uint4* dq = (uint4*)dst;
    dq[0]=rv[0]; dq[1]=rv[1]; dq[2]=rv[2]; dq[3]=rv[3];
  }
}

// ---------------- OLD monolithic scan (fallback if workspace too small) ----------------
__global__ __launch_bounds__(128) void k_scan(const ushort_t* __restrict__ fac0,
    const ushort_t* __restrict__ fac1,
    const float* __restrict__ momw, const float* __restrict__ decw,
    float* __restrict__ out){
  int blk = blockIdx.x;
  int bh = blk & 7; int rest = blk >> 3;
  int ig = rest >> 3, jb = rest & 7;
  int i0 = ig*16, j0 = jb*16;
  int tid = threadIdx.x;
  int wv = tid >> 6, lane = tid & 63;
  int quad = lane >> 4, rrow = lane & 15;
  __shared__ __align__(16) ushort_t sbuf[2][1024];
  const ushort_t* gsl = (wv==0)
      ? fac0 + ((size_t)bh*NCX*128 + (size_t)i0)*32
      : fac1 + ((size_t)bh*NCX*128 + (size_t)j0)*32;

  f32x4 m_ = {0.f,0.f,0.f,0.f};
  f32x4 u_ = {0.f,0.f,0.f,0.f};
  const f32x4 zero = {0.f,0.f,0.f,0.f};
  size_t obase = ((size_t)(wv*BHX + bh)*NCX)*((size_t)DHX*DHX) + (size_t)i0*DHX + j0;
  const float* mop = momw + bh*NCX;
  const float* dep = decw + bh*NCX;

  gl_lds16((const void*)(gsl + (size_t)lane*8), (void*)&sbuf[0][wv*512]);
  __syncthreads();
  int b = 0;
  for (int t=0; t<NCX; t++){
    if (t+1 < NCX)
      gl_lds16((const void*)(gsl + (size_t)(t+1)*4096 + (size_t)lane*8),
               (void*)&sbuf[b^1][wv*512]);
    float mo = mop[t], de = dep[t];
    bf16x8 fa = {0,0,0,0,0,0,0,0};
    bf16x8 fb = {0,0,0,0,0,0,0,0};
    if (quad < 2){
      fa = *(const bf16x8*)&sbuf[b][      rrow*32 + wv*16 + quad*8];
      fb = *(const bf16x8*)&sbuf[b][512 + rrow*32 + wv*16 + quad*8];
    }
    f32x4 g = __builtin_amdgcn_mfma_f32_16x16x32_bf16(fa, fb, zero, 0, 0, 0);
    size_t ob = obase + (size_t)t*(DHX*DHX);
    #pragma unroll
    for (int r=0;r<4;r++){
      m_[r] = mo*m_[r] - g[r];
      u_[r] = de*u_[r] + m_[r];
      out[ob + (size_t)(quad*4+r)*DHX + rrow] = u_[r];
    }
    __syncthreads();
    b ^= 1;
  }
}

// ---------------- S1: per-segment local scan summaries ----------------
// grid 3584 = 8 bh * 7 sg * 64 tiles, 128 threads (wv0 -> u0/fac0, wv1 -> u1/fac1)
// carry layout: [ ((wv*8+bh)*64 + tile)*8 + sg ] * 512 floats: m at [0..255], u at [256..511]
// element e = r*64 + lane  <->  tile element (row = quad*4+r, col = rrow)
__global__ __launch_bounds__(128, 8) void k_scan_sum(const ushort_t* __restrict__ fac0,
    const ushort_t* __restrict__ fac1,
    const float* __restrict__ momw, const float* __restrict__ decw,
    float* __restrict__ carry){
  int blk = blockIdx.x;
  int bh = blk & 7;
  int rest = blk >> 3;            // tile*7 + sg
  int sg = rest % 7;              // only segments 0..6 need summaries
  int tile = rest / 7;
  int ig = tile >> 3, jb = tile & 7;
  int i0 = ig*16, j0 = jb*16;
  int tid = threadIdx.x;
  int wv = tid >> 6, lane = tid & 63;
  int quad = lane >> 4, rrow = lane & 15;
  __shared__ __align__(16) ushort_t sbuf[2][1024];
  const ushort_t* gsl = (wv==0)
      ? fac0 + (((size_t)bh*NCX + sg*SEGL)*128 + (size_t)i0)*32
      : fac1 + (((size_t)bh*NCX + sg*SEGL)*128 + (size_t)j0)*32;

  f32x4 m_ = {0.f,0.f,0.f,0.f};
  f32x4 u_ = {0.f,0.f,0.f,0.f};
  const f32x4 zero = {0.f,0.f,0.f,0.f};
  const float* mop = momw + bh*NCX + sg*SEGL;
  const float* dep = decw + bh*NCX + sg*SEGL;

  gl_lds16((const void*)(gsl + (size_t)lane*8), (void*)&sbuf[0][wv*512]);
  __syncthreads();
  int b = 0;
  for (int t=0; t<SEGL; t++){
    if (t+1 < SEGL)
      gl_lds16((const void*)(gsl + (size_t)(t+1)*4096 + (size_t)lane*8),
               (void*)&sbuf[b^1][wv*512]);
    float mo = mop[t], de = dep[t];
    bf16x8 fa = {0,0,0,0,0,0,0,0};
    bf16x8 fb = {0,0,0,0,0,0,0,0};
    if (quad < 2){
      fa = *(const bf16x8*)&sbuf[b][      rrow*32 + wv*16 + quad*8];
      fb = *(const bf16x8*)&sbuf[b][512 + rrow*32 + wv*16 + quad*8];
    }
    f32x4 g = __builtin_amdgcn_mfma_f32_16x16x32_bf16(fa, fb, zero, 0, 0, 0);
    #pragma unroll
    for (int r=0;r<4;r++){
      m_[r] = mo*m_[r] - g[r];
      u_[r] = de*u_[r] + m_[r];
    }
    __syncthreads();
    b ^= 1;
  }
  size_t base = ((((size_t)wv*8 + bh)*64 + tile)*8 + sg)*512;
  #pragma unroll
  for (int r=0;r<4;r++){
    carry[base +       r*64 + lane] = m_[r];
    carry[base + 256 + r*64 + lane] = u_[r];
  }
}

// ---------------- S2: cross-segment affine carry scan (in-place) ----------------
// grid 1024 = (wv*8+bh)*64 + tile, 256 threads (one per tile element)
// After this kernel, slot sg holds the INCOMING (m,u) state for segment sg.
__global__ __launch_bounds__(256) void k_scan_carry(const float* __restrict__ momw,
    const float* __restrict__ decw, float* __restrict__ carry){
  int blk = blockIdx.x;
  int bh = (blk >> 6) & 7;
  int j = threadIdx.x;
  size_t base = (size_t)blk * 4096;
  const float* mop = momw + bh*NCX;
  const float* dep = decw + bh*NCX;
  float m = 0.f, u = 0.f;
  for (int sg=0; sg<NSEG; sg++){
    float gm = 0.f, gu = 0.f;
    if (sg < NSEG-1){
      gm = carry[base + (size_t)sg*512 + j];
      gu = carry[base + (size_t)sg*512 + 256 + j];
    }
    carry[base + (size_t)sg*512 + j]       = m;
    carry[base + (size_t)sg*512 + 256 + j] = u;
    if (sg < NSEG-1){
      // per-segment affine map scalars: A = prod(mo), D = prod(de), C = cross term
      float A = 1.f, C = 0.f, D = 1.f;
      #pragma unroll
      for (int t=0; t<SEGL; t++){
        float mo = mop[sg*SEGL + t], de = dep[sg*SEGL + t];
        A = mo*A;
        C = de*C + A;
        D = de*D;
      }
      float nm = A*m + gm;
      u = C*m + D*u + gu;
      m = nm;
    }
  }
}

// ---------------- S3: apply — local scan with incoming state, write final u ----------------
// grid 4096 = bh(3b) | sg(3b) | tile(6b), 128 threads
__global__ __launch_bounds__(128, 8) void k_scan_fix(const ushort_t* __restrict__ fac0,
    const ushort_t* __restrict__ fac1,
    const float* __restrict__ momw, const float* __restrict__ decw,
    const float* __restrict__ carry, float* __restrict__ out){
  int blk = blockIdx.x;
  int bh = blk & 7;
  int sg = (blk >> 3) & 7;
  int tile = blk >> 6;
  int ig = tile >> 3, jb = tile & 7;
  int i0 = ig*16, j0 = jb*16;
  int tid = threadIdx.x;
  int wv = tid >> 6, lane = tid & 63;
  int quad = lane >> 4, rrow = lane & 15;
  __shared__ __align__(16) ushort_t sbuf[2][1024];
  const ushort_t* gsl = (wv==0)
      ? fac0 + (((size_t)bh*NCX + sg*SEGL)*128 + (size_t)i0)*32
      : fac1 + (((size_t)bh*NCX + sg*SEGL)*128 + (size_t)j0)*32;

  f32x4 m_, u_;
  size_t cb = ((((size_t)wv*8 + bh)*64 + tile)*8 + sg)*512;
  #pragma unroll
  for (int r=0;r<4;r++){
    m_[r] = carry[cb +       r*64 + lane];
    u_[r] = carry[cb + 256 + r*64 + lane];
  }
  const f32x4 zero = {0.f,0.f,0.f,0.f};
  size_t obase = (((size_t)(wv*BHX + bh)*NCX) + sg*SEGL)*((size_t)DHX*DHX)
               + (size_t)i0*DHX + j0;
  const float* mop = momw + bh*NCX + sg*SEGL;
  const float* dep = decw + bh*NCX + sg*SEGL;

  gl_lds16((const void*)(gsl + (size_t)lane*8), (void*)&sbuf[0][wv*512]);
  __syncthreads();
  int b = 0;
  for (int t=0; t<SEGL; t++){
    if (t+1 < SEGL)
      gl_lds16((const void*)(gsl + (size_t)(t+1)*4096 + (size_t)lane*8),
               (void*)&sbuf[b^1][wv*512]);
    float mo = mop[t], de = dep[t];
    bf16x8 fa = {0,0,0,0,0,0,0,0};
    bf16x8 fb = {0,0,0,0,0,0,0,0};
    if (quad < 2){
      fa = *(const bf16x8*)&sbuf[b][      rrow*32 + wv*16 + quad*8];
      fb = *(const bf16x8*)&sbuf[b][512 + rrow*32 + wv*16 + quad*8];
    }
    f32x4 g = __builtin_amdgcn_mfma_f32_16x16x32_bf16(fa, fb, zero, 0, 0, 0);
    size_t ob = obase + (size_t)t*(DHX*DHX);
    #pragma unroll
    for (int r=0;r<4;r++){
      m_[r] = mo*m_[r] - g[r];
      u_[r] = de*u_[r] + m_[r];
      out[ob + (size_t)(quad*4+r)*DHX + rrow] = u_[r];
    }
    __syncthreads();
    b ^= 1;
  }
}

extern "C" void kernel_launch(void* const* d_in, const int* in_sizes, int n_in,
                              void* d_out, int out_size, void* d_ws, size_t ws_size,
                              hipStream_t stream) {
  (void)in_sizes; (void)n_in; (void)out_size;
  const float* seq   = (const float*)d_in[0];
  const float* scale = (const float*)d_in[1];
  const float* Wkv   = (const float*)d_in[2];
  const float* Wstep = (const float*)d_in[3];
  const float* Wmom  = (const float*)d_in[4];
  const float* Wdec  = (const float*)d_in[5];
  const float* w0    = (const float*)d_in[6];
  const float* w1    = (const float*)d_in[7];
  float* out = (float*)d_out;
  float* ws  = (float*)d_ws;

  // workspace layout (float units)
  float*    x     = ws;                          // 2,097,152
  ushort_t* fac0  = (ushort_t*)(ws + 2097152);   // 4,194,304 ushorts
  ushort_t* fac1  = (ushort_t*)(ws + 4194304);   // 4,194,304 ushorts
  ushort_t* WkvT  = (ushort_t*)(ws + 6291456);   // 524,288 ushorts
  ushort_t* w0T   = (ushort_t*)(ws + 6553600);   // 131,072 ushorts
  ushort_t* w1T   = (ushort_t*)(ws + 6619136);   // 131,072 ushorts
  ushort_t* w1n   = (ushort_t*)(ws + 6684672);   // 131,072 ushorts
  float*    lrArr = ws + 6750208;                // 16,384
  float*    momw  = ws + 6766592;                // 1,024
  float*    decw  = ws + 6767616;                // 1,024
  float*    carry = ws + 6768640;                // 4,194,304 (segmented-scan states)
  const size_t need_bytes = (size_t)(6768640 + 4194304) * sizeof(float);

  k_prep<<<dim3(72), dim3(256), 0, stream>>>(Wkv, w0, w1, WkvT, w0T, w1T, w1n);
  k_rms_lr<<<dim3(BX*SX), dim3(256), 0, stream>>>(seq, scale, Wstep, x, lrArr);
  k_stats<<<dim3(BX*NCX), dim3(64), 0, stream>>>(x, Wmom, Wdec, momw, decw);
  k_fused<<<dim3(BHX*NCX), dim3(256), 0, stream>>>(x, WkvT, w0T, w1T, w1n, lrArr, fac0, fac1);

  if (ws_size >= need_bytes) {
    // segmented scan: 8x the latency-hiding parallelism of the monolithic scan
    k_scan_sum<<<dim3(8*7*64), dim3(128), 0, stream>>>(fac0, fac1, momw, decw, carry);
    k_scan_carry<<<dim3(1024), dim3(256), 0, stream>>>(momw, decw, carry);
    k_scan_fix<<<dim3(8*8*64), dim3(128), 0, stream>>>(fac0, fac1, momw, decw, carry, out);
  } else {
    k_scan<<<dim3(512), dim3(128), 0, stream>>>(fac0, fac1, momw, decw, out);
  }
}

// Round 2
// 246.279 us; speedup vs baseline: 1.2867x; 1.2867x over previous
//
#include <hip/hip_runtime.h>

#define DIMX 512
#define HEADSX 4
#define DHX 128
#define CHX 16
#define NCX 128
#define SX 2048
#define BX 2
#define BHX 8
#define PADX 520   // xs LDS row pad (ushorts): banks (4c + kk/2) -> worst 2-way (free)
#define PADF 136   // factor LDS row pad (ushorts): same property

typedef unsigned short ushort_t;
typedef unsigned int uint_t;
typedef short bf16x8 __attribute__((ext_vector_type(8)));
typedef float f32x4 __attribute__((ext_vector_type(4)));

__device__ __forceinline__ float sigmoidf_(float z){ return 1.0f/(1.0f + __expf(-z)); }

// fp32 -> bf16 round-to-nearest-even
__device__ __forceinline__ ushort_t f2bf(float f){
  uint_t u = __float_as_uint(f);
  return (ushort_t)((u + 0x7FFFu + ((u >> 16) & 1u)) >> 16);
}
__device__ __forceinline__ uint_t pk2(float a, float b){
  return (uint_t)f2bf(a) | ((uint_t)f2bf(b) << 16);
}

// ---------------- K1: RMSNorm + per-token adaptive lr ----------------
__global__ __launch_bounds__(256) void k_rms_lr(const float* __restrict__ seq,
    const float* __restrict__ scale, const float* __restrict__ Wstep,
    float* __restrict__ x, float* __restrict__ lrArr){
  int tok = blockIdx.x; int tid = threadIdx.x;
  const float* row = seq + (size_t)tok*DIMX;
  float v0 = row[tid], v1 = row[tid+256];
  float ss = v0*v0 + v1*v1;
  #pragma unroll
  for (int o=32;o>0;o>>=1) ss += __shfl_down(ss,o,64);
  __shared__ float red[4];
  __shared__ float rs_s;
  int wv = tid>>6, ln = tid&63;
  if (ln==0) red[wv]=ss;
  __syncthreads();
  if (tid==0){
    float ms = (red[0]+red[1]+red[2]+red[3]) * (1.0f/DIMX);
    rs_s = 1.0f/sqrtf(ms + 1e-6f);
  }
  __syncthreads();
  float rs = rs_s;
  float x0 = v0*rs*scale[tid];
  float x1 = v1*rs*scale[tid+256];
  size_t xo = (size_t)tok*DIMX;
  x[xo+tid]=x0; x[xo+tid+256]=x1;
  float a0 = x0*Wstep[tid*4+0] + x1*Wstep[(tid+256)*4+0];
  float a1 = x0*Wstep[tid*4+1] + x1*Wstep[(tid+256)*4+1];
  float a2 = x0*Wstep[tid*4+2] + x1*Wstep[(tid+256)*4+2];
  float a3 = x0*Wstep[tid*4+3] + x1*Wstep[(tid+256)*4+3];
  #pragma unroll
  for (int o=32;o>0;o>>=1){
    a0 += __shfl_down(a0,o,64); a1 += __shfl_down(a1,o,64);
    a2 += __shfl_down(a2,o,64); a3 += __shfl_down(a3,o,64);
  }
  __shared__ float red4[4][4];
  if (ln==0){ red4[wv][0]=a0; red4[wv][1]=a1; red4[wv][2]=a2; red4[wv][3]=a3; }
  __syncthreads();
  if (tid<4){
    float d = red4[0][tid]+red4[1][tid]+red4[2][tid]+red4[3][tid];
    int b = tok>>11, s = tok&2047;
    lrArr[(size_t)(b*HEADSX+tid)*SX + s] = 0.01f * sigmoidf_(d);
  }
}

// ---------------- K2: per-chunk mean -> mom / (1-dec) ----------------
__global__ __launch_bounds__(64) void k_stats(const float* __restrict__ x,
    const float* __restrict__ Wmom, const float* __restrict__ Wdec,
    float* __restrict__ momw, float* __restrict__ decw){
  int blk = blockIdx.x; int b = blk>>7, nc = blk&127; int ln = threadIdx.x;
  float am[4]={0,0,0,0}, ad[4]={0,0,0,0};
  const float* base = x + ((size_t)(b*SX + nc*CHX))*DIMX;
  for (int r=0;r<8;r++){
    int d = ln + 64*r;
    float m = 0.0f;
    #pragma unroll
    for (int c=0;c<CHX;c++) m += base[(size_t)c*DIMX + d];
    m *= (1.0f/CHX);
    #pragma unroll
    for (int h=0;h<4;h++){ am[h]+=m*Wmom[d*4+h]; ad[h]+=m*Wdec[d*4+h]; }
  }
  #pragma unroll
  for (int h=0;h<4;h++){
    #pragma unroll
    for (int o=32;o>0;o>>=1){ am[h]+=__shfl_down(am[h],o,64); ad[h]+=__shfl_down(ad[h],o,64); }
  }
  if (ln==0){
    #pragma unroll
    for (int h=0;h<4;h++){
      momw[(b*HEADSX+h)*NCX + nc] = sigmoidf_(am[h]);
      decw[(b*HEADSX+h)*NCX + nc] = 1.0f - sigmoidf_(ad[h]);
    }
  }
}

// ---------------- K-prep: bf16 weight layouts ----------------
// WkvT path now transposes through LDS: both the Wkv read and the WkvT write
// are fully coalesced (the old path wrote 2B per lane at 64B stride = 32x amp).
__global__ __launch_bounds__(256) void k_prep(const float* __restrict__ Wkv,
    const float* __restrict__ w0, const float* __restrict__ w1,
    ushort_t* __restrict__ WkvT, ushort_t* __restrict__ w0T,
    ushort_t* __restrict__ w1T, ushort_t* __restrict__ w1n){
  int blk = blockIdx.x; int tid = threadIdx.x;
  if (blk < 64){
    int h = blk >> 4, kt = blk & 15;
    __shared__ ushort_t tile[256][33];   // [col][kk], +1 pad
    for (int i=tid; i<8192; i+=256){
      int kk = i >> 8, col = i & 255;    // consecutive i -> consecutive col: coalesced read
      int wcol = (col < 128) ? (h*128 + col) : (384 + h*128 + col);
      float v = Wkv[(size_t)(kt*32+kk)*1024 + wcol];
      tile[col][kk] = f2bf(v);
    }
    __syncthreads();
    for (int i=tid; i<8192; i+=256){
      int col = i >> 5, kk = i & 31;     // consecutive i -> consecutive kk: coalesced write
      WkvT[(((size_t)h*16 + kt)*256 + col)*32 + kk] = tile[col][kk];
    }
  } else {
    int bh = blk - 64;
    size_t base = (size_t)bh*16384;
    for (int i=tid; i<16384; i+=256){
      int r = i >> 7, c = i & 127;
      w0T[base + i] = f2bf(w0[base + (size_t)c*128 + r]);
      w1T[base + i] = f2bf(w1[base + (size_t)c*128 + r]);
      w1n[base + i] = f2bf(w1[base + i]);
    }
  }
}

// ---------------- K-fused: kv projection + per-chunk gradient factors, all MFMA ----------------
__global__ __launch_bounds__(256) void k_fused(const float* __restrict__ x,
    const ushort_t* __restrict__ WkvT, const ushort_t* __restrict__ w0T,
    const ushort_t* __restrict__ w1T, const ushort_t* __restrict__ w1n,
    const float* __restrict__ lrArr,
    ushort_t* __restrict__ fac0, ushort_t* __restrict__ fac1){
  int blk = blockIdx.x;
  int bh = blk & 7, t = blk >> 3;
  int b = bh >> 2, h = bh & 3;
  int bt = bh*NCX + t;
  __shared__ __align__(16) ushort_t xs[16*PADX];
  __shared__ __align__(16) ushort_t ks[16*PADF];
  __shared__ __align__(16) ushort_t as_[16*PADF];
  __shared__ __align__(16) ushort_t dp_[16*PADF];
  __shared__ __align__(16) ushort_t dh_[16*PADF];
  int tid = threadIdx.x;
  int wv = tid>>6, lane = tid&63;
  int quad = lane>>4, nl = lane&15;
  const f32x4 zero = {0.f,0.f,0.f,0.f};

  const float* xb = x + ((size_t)(b*SX + t*CHX))*DIMX;
  #pragma unroll
  for (int it=0; it<8; it++){
    int f = tid + 256*it;
    int c = f >> 7, k4 = f & 127;
    float4 q = ((const float4*)xb)[(size_t)c*128 + k4];
    uint2 u; u.x = pk2(q.x,q.y); u.y = pk2(q.z,q.w);
    *(uint2*)&xs[c*PADX + k4*4] = u;
  }
  __syncthreads();

  // ---- KV gemm: M=16 (c), N=256 (k|v cols), K=512
  f32x4 kacc[2] = {zero, zero};
  f32x4 vacc[2] = {zero, zero};
  const ushort_t* wkvh = WkvT + (size_t)h*16*256*32;
  for (int kt=0; kt<16; kt++){
    bf16x8 Af = *(const bf16x8*)&xs[nl*PADX + kt*32 + quad*8];
    #pragma unroll
    for (int s=0; s<2; s++){
      int ktile = 2*wv + s;
      bf16x8 Bk = *(const bf16x8*)&wkvh[((size_t)kt*256 + (ktile*16+nl))*32 + quad*8];
      kacc[s] = __builtin_amdgcn_mfma_f32_16x16x32_bf16(Af, Bk, kacc[s], 0,0,0);
      int vtile = 8 + 2*wv + s;
      bf16x8 Bv = *(const bf16x8*)&wkvh[((size_t)kt*256 + (vtile*16+nl))*32 + quad*8];
      vacc[s] = __builtin_amdgcn_mfma_f32_16x16x32_bf16(Af, Bv, vacc[s], 0,0,0);
    }
  }
  #pragma unroll
  for (int s=0;s<2;s++){
    #pragma unroll
    for (int r=0;r<4;r++)
      ks[(quad*4+r)*PADF + 32*wv + 16*s + nl] = f2bf(kacc[s][r]);
  }
  __syncthreads();

  // ---- gemm1: h = k @ w0
  const ushort_t* w0b = w0T + (size_t)bh*16384;
  f32x4 hacc[2] = {zero, zero};
  for (int kt=0; kt<4; kt++){
    bf16x8 Af = *(const bf16x8*)&ks[nl*PADF + kt*32 + quad*8];
    #pragma unroll
    for (int s=0; s<2; s++){
      int n0 = (2*wv+s)*16;
      bf16x8 Bf = *(const bf16x8*)&w0b[(size_t)(n0+nl)*128 + kt*32 + quad*8];
      hacc[s] = __builtin_amdgcn_mfma_f32_16x16x32_bf16(Af, Bf, hacc[s], 0,0,0);
    }
  }
  float sp[2][4];
  #pragma unroll
  for (int s=0;s<2;s++){
    #pragma unroll
    for (int r=0;r<4;r++){
      float hh = hacc[s][r];
      float sg = sigmoidf_(hh);
      float a  = hh*sg;
      sp[s][r] = sg*(1.0f + hh*(1.0f-sg));
      as_[(quad*4+r)*PADF + 32*wv + 16*s + nl] = f2bf(a);
    }
  }
  __syncthreads();

  // ---- gemm2: pred = a @ w1 ; dpred = 2/DH * lr * (pred - v)
  const ushort_t* w1tb = w1T + (size_t)bh*16384;
  f32x4 pacc[2] = {zero, zero};
  for (int kt=0; kt<4; kt++){
    bf16x8 Af = *(const bf16x8*)&as_[nl*PADF + kt*32 + quad*8];
    #pragma unroll
    for (int s=0; s<2; s++){
      int n0 = (2*wv+s)*16;
      bf16x8 Bf = *(const bf16x8*)&w1tb[(size_t)(n0+nl)*128 + kt*32 + quad*8];
      pacc[s] = __builtin_amdgcn_mfma_f32_16x16x32_bf16(Af, Bf, pacc[s], 0,0,0);
    }
  }
  float lrv[4];
  #pragma unroll
  for (int r=0;r<4;r++) lrv[r] = lrArr[(size_t)bh*SX + t*CHX + quad*4 + r];
  #pragma unroll
  for (int s=0;s<2;s++){
    #pragma unroll
    for (int r=0;r<4;r++){
      float dp = (2.0f/DHX)*lrv[r]*(pacc[s][r] - vacc[s][r]);
      dp_[(quad*4+r)*PADF + 32*wv + 16*s + nl] = f2bf(dp);
    }
  }
  __syncthreads();

  // ---- gemm3: da = dpred @ w1^T ; dh0 = da * silu'(h)
  const ushort_t* w1nb = w1n + (size_t)bh*16384;
  f32x4 dacc[2] = {zero, zero};
  for (int kt=0; kt<4; kt++){
    bf16x8 Af = *(const bf16x8*)&dp_[nl*PADF + kt*32 + quad*8];
    #pragma unroll
    for (int s=0; s<2; s++){
      int n0 = (2*wv+s)*16;
      bf16x8 Bf = *(const bf16x8*)&w1nb[(size_t)(n0+nl)*128 + kt*32 + quad*8];
      dacc[s] = __builtin_amdgcn_mfma_f32_16x16x32_bf16(Af, Bf, dacc[s], 0,0,0);
    }
  }
  #pragma unroll
  for (int s=0;s<2;s++){
    #pragma unroll
    for (int r=0;r<4;r++)
      dh_[(quad*4+r)*PADF + 32*wv + 16*s + nl] = f2bf(dacc[s][r]*sp[s][r]);
  }
  __syncthreads();

  // ---- pack: fac0 row p = {k c0..15 | a c0..15}, fac1 row p = {dh c0..15 | dp c0..15}
  {
    int p = tid & 127, which = tid >> 7;
    const ushort_t* s0 = which ? dh_ : ks;
    const ushort_t* s1 = which ? dp_ : as_;
    ushort_t rowv[32];
    #pragma unroll
    for (int c=0;c<16;c++){ rowv[c] = s0[c*PADF + p]; rowv[16+c] = s1[c*PADF + p]; }
    ushort_t* dst = (which ? fac1 : fac0) + ((size_t)bt*128 + p)*32;
    const uint4* rv = (const uint4*)rowv;
    uint4* dq = (uint4*)dst;
    dq[0]=rv[0]; dq[1]=rv[1]; dq[2]=rv[2]; dq[3]=rv[3];
  }
}

// ---------------- K-scan3: barrier-free, LDS-free MFMA scan ----------------
// 1024 blocks x 64 threads: blk = bh | jb<<3 | ig<<6 | mat<<9 (bh in low bits
// keeps each bh's 2MB fac slice on one XCD's L2). One wave owns one
// (mat, i-tile, j-tile) task for all 128 chunks.
//
// Key insight: the mfma_f32_16x16x32_bf16 A/B fragment layout (lane l holds
// row/col l&15, k = (l>>4)*8..+7, 16B contiguous) exactly matches the fac
// row-major layout, so fragments load straight global->VGPR as coalesced
// dwordx4. No LDS staging, no __syncthreads, so output stores never gate a
// vmcnt(0) drain -- they just stream at HBM write bandwidth. Register
// prefetch 2 chunks deep; the compiler inserts precise per-use s_waitcnt.
__global__ __launch_bounds__(64) void k_scan3(const ushort_t* __restrict__ fac0,
    const ushort_t* __restrict__ fac1,
    const float* __restrict__ momw, const float* __restrict__ decw,
    float* __restrict__ out){
  int blk = blockIdx.x;
  int bh  = blk & 7;
  int jb  = (blk >> 3) & 7;
  int ig  = (blk >> 6) & 7;
  int mat = blk >> 9;
  int lane = threadIdx.x;
  int quad = lane >> 4, rrow = lane & 15;
  const f32x4 zero = {0.f,0.f,0.f,0.f};
  const bf16x8 fz = {0,0,0,0,0,0,0,0};

  // fa: fac0 rows i0+rrow, half mat (0: k-part, 1: a-part); fb: fac1 rows j0+rrow
  // (0: dh-part, 1: dp-part). t-stride = 128 rows * 32 ushorts = 4096 ushorts.
  size_t rowbase = (size_t)bh*NCX*128;
  const ushort_t* pa = fac0 + (rowbase + (size_t)(ig*16 + rrow))*32 + mat*16 + quad*8;
  const ushort_t* pb = fac1 + (rowbase + (size_t)(jb*16 + rrow))*32 + mat*16 + quad*8;
  bool act = (quad < 2);   // chunks 16..31 of the K dim are zero padding

  bf16x8 fa0=fz, fb0=fz, fa1=fz, fb1=fz;
  if (act){
    fa0 = *(const bf16x8*)(pa);
    fb0 = *(const bf16x8*)(pb);
    fa1 = *(const bf16x8*)(pa + 4096);
    fb1 = *(const bf16x8*)(pb + 4096);
  }

  f32x4 m_ = zero, u_ = zero;
  // fold the lane's (row,col) into the output base
  size_t obase = ((size_t)(mat*BHX + bh)*NCX)*((size_t)DHX*DHX)
               + (size_t)(ig*16 + quad*4)*DHX + (size_t)(jb*16 + rrow);
  const float* mop = momw + bh*NCX;
  const float* dep = decw + bh*NCX;

  for (int t=0; t<NCX; t+=2){
    bf16x8 na0=fz, nb0=fz, na1=fz, nb1=fz;
    if (act && (t+2 < NCX)){
      na0 = *(const bf16x8*)(pa + (size_t)(t+2)*4096);
      nb0 = *(const bf16x8*)(pb + (size_t)(t+2)*4096);
      na1 = *(const bf16x8*)(pa + (size_t)(t+3)*4096);
      nb1 = *(const bf16x8*)(pb + (size_t)(t+3)*4096);
    }
    float mo = mop[t], de = dep[t];
    f32x4 g = __builtin_amdgcn_mfma_f32_16x16x32_bf16(fa0, fb0, zero, 0,0,0);
    float* ob = out + obase + (size_t)t*(DHX*DHX);
    #pragma unroll
    for (int r=0;r<4;r++){
      m_[r] = mo*m_[r] - g[r];
      u_[r] = de*u_[r] + m_[r];
      ob[(size_t)r*DHX] = u_[r];
    }
    mo = mop[t+1]; de = dep[t+1];
    g = __builtin_amdgcn_mfma_f32_16x16x32_bf16(fa1, fb1, zero, 0,0,0);
    ob += (size_t)DHX*DHX;
    #pragma unroll
    for (int r=0;r<4;r++){
      m_[r] = mo*m_[r] - g[r];
      u_[r] = de*u_[r] + m_[r];
      ob[(size_t)r*DHX] = u_[r];
    }
    fa0=na0; fb0=nb0; fa1=na1; fb1=nb1;
  }
}

extern "C" void kernel_launch(void* const* d_in, const int* in_sizes, int n_in,
                              void* d_out, int out_size, void* d_ws, size_t ws_size,
                              hipStream_t stream) {
  (void)in_sizes; (void)n_in; (void)out_size; (void)ws_size;
  const float* seq   = (const float*)d_in[0];
  const float* scale = (const float*)d_in[1];
  const float* Wkv   = (const float*)d_in[2];
  const float* Wstep = (const float*)d_in[3];
  const float* Wmom  = (const float*)d_in[4];
  const float* Wdec  = (const float*)d_in[5];
  const float* w0    = (const float*)d_in[6];
  const float* w1    = (const float*)d_in[7];
  float* out = (float*)d_out;
  float* ws  = (float*)d_ws;

  // workspace layout (float units)
  float*    x     = ws;                          // 2,097,152
  ushort_t* fac0  = (ushort_t*)(ws + 2097152);   // 4,194,304 ushorts
  ushort_t* fac1  = (ushort_t*)(ws + 4194304);   // 4,194,304 ushorts
  ushort_t* WkvT  = (ushort_t*)(ws + 6291456);   // 524,288 ushorts
  ushort_t* w0T   = (ushort_t*)(ws + 6553600);   // 131,072 ushorts
  ushort_t* w1T   = (ushort_t*)(ws + 6619136);   // 131,072 ushorts
  ushort_t* w1n   = (ushort_t*)(ws + 6684672);   // 131,072 ushorts
  float*    lrArr = ws + 6750208;                // 16,384
  float*    momw  = ws + 6766592;                // 1,024
  float*    decw  = ws + 6767616;                // 1,024

  k_prep<<<dim3(72), dim3(256), 0, stream>>>(Wkv, w0, w1, WkvT, w0T, w1T, w1n);
  k_rms_lr<<<dim3(BX*SX), dim3(256), 0, stream>>>(seq, scale, Wstep, x, lrArr);
  k_stats<<<dim3(BX*NCX), dim3(64), 0, stream>>>(x, Wmom, Wdec, momw, decw);
  k_fused<<<dim3(BHX*NCX), dim3(256), 0, stream>>>(x, WkvT, w0T, w1T, w1n, lrArr, fac0, fac1);
  k_scan3<<<dim3(1024), dim3(64), 0, stream>>>(fac0, fac1, momw, decw, out);
}

// Round 3
// 233.710 us; speedup vs baseline: 1.3559x; 1.0538x over previous
//
#include <hip/hip_runtime.h>

#define DIMX 512
#define HEADSX 4
#define DHX 128
#define CHX 16
#define NCX 128
#define SX 2048
#define BX 2
#define BHX 8
#define PADX 520   // xs LDS row pad (ushorts): banks (4c + kk/2) -> worst 2-way (free)
#define PADF 136   // factor LDS row pad (ushorts): same property

typedef unsigned short ushort_t;
typedef unsigned int uint_t;
typedef short bf16x8 __attribute__((ext_vector_type(8)));
typedef float f32x4 __attribute__((ext_vector_type(4)));

__device__ __forceinline__ float sigmoidf_(float z){ return 1.0f/(1.0f + __expf(-z)); }

// fp32 -> bf16 round-to-nearest-even
__device__ __forceinline__ ushort_t f2bf(float f){
  uint_t u = __float_as_uint(f);
  return (ushort_t)((u + 0x7FFFu + ((u >> 16) & 1u)) >> 16);
}
__device__ __forceinline__ uint_t pk2(float a, float b){
  return (uint_t)f2bf(a) | ((uint_t)f2bf(b) << 16);
}

// ---------------- K-prep: bf16 weight layouts ----------------
__global__ __launch_bounds__(256) void k_prep(const float* __restrict__ Wkv,
    const float* __restrict__ w0, const float* __restrict__ w1,
    ushort_t* __restrict__ WkvT, ushort_t* __restrict__ w0T,
    ushort_t* __restrict__ w1T, ushort_t* __restrict__ w1n){
  int blk = blockIdx.x; int tid = threadIdx.x;
  if (blk < 64){
    int h = blk >> 4, kt = blk & 15;
    __shared__ ushort_t tile[256][33];   // [col][kk], +1 pad
    for (int i=tid; i<8192; i+=256){
      int kk = i >> 8, col = i & 255;    // consecutive i -> consecutive col: coalesced read
      int wcol = (col < 128) ? (h*128 + col) : (384 + h*128 + col);
      float v = Wkv[(size_t)(kt*32+kk)*1024 + wcol];
      tile[col][kk] = f2bf(v);
    }
    __syncthreads();
    for (int i=tid; i<8192; i+=256){
      int col = i >> 5, kk = i & 31;     // consecutive i -> consecutive kk: coalesced write
      WkvT[(((size_t)h*16 + kt)*256 + col)*32 + kk] = tile[col][kk];
    }
  } else {
    int bh = blk - 64;
    size_t base = (size_t)bh*16384;
    for (int i=tid; i<16384; i+=256){
      int r = i >> 7, c = i & 127;
      w0T[base + i] = f2bf(w0[base + (size_t)c*128 + r]);
      w1T[base + i] = f2bf(w1[base + (size_t)c*128 + r]);
      w1n[base + i] = f2bf(w1[base + i]);
    }
  }
}

// ---------------- K-fused2: RMSNorm + lr + mom/dec + kv proj + gradient factors ----------------
// 1024 blocks (bh = blk&7 for XCD L2 locality, t = blk>>3), 256 threads = 4 waves.
// Phase 0 replaces the old k_rms_lr + k_stats kernels entirely:
//   rs_c   = 1/sqrt(mean_d seq^2 + eps)                        (per token)
//   lr_c   = 0.01*sigmoid(rs_c * sum_d seq*scale*Wstep[:,h])   (per token; sum reorder)
//   mom    = sigmoid( (1/16) sum_c rs_c * P_c^mom )            (per chunk; sum reorder)
//   dec    = 1 - sigmoid( (1/16) sum_c rs_c * P_c^dec )
// so no x round-trip through HBM and no lrArr; the normalized bf16 x goes
// straight into LDS for the MFMA chain.
__global__ __launch_bounds__(256) void k_fused2(const float* __restrict__ seq,
    const float* __restrict__ scale, const float* __restrict__ Wstep,
    const float* __restrict__ Wmom, const float* __restrict__ Wdec,
    const ushort_t* __restrict__ WkvT, const ushort_t* __restrict__ w0T,
    const ushort_t* __restrict__ w1T, const ushort_t* __restrict__ w1n,
    ushort_t* __restrict__ fac0, ushort_t* __restrict__ fac1,
    float* __restrict__ momw, float* __restrict__ decw){
  int blk = blockIdx.x;
  int bh = blk & 7, t = blk >> 3;
  int b = bh >> 2, h = bh & 3;
  int bt = bh*NCX + t;
  __shared__ __align__(16) ushort_t xs[16*PADX];
  __shared__ __align__(16) ushort_t ks[16*PADF];
  __shared__ __align__(16) ushort_t as_[16*PADF];
  __shared__ __align__(16) ushort_t dp_[16*PADF];
  __shared__ __align__(16) ushort_t dh_[16*PADF];
  __shared__ float red[4][8][4];     // [wave][it][ss,lp,pm,pd]
  __shared__ float rs_s[16], lr_s[16];
  int tid = threadIdx.x;
  int wv = tid>>6, lane = tid&63;
  int quad = lane>>4, nl = lane&15;
  const f32x4 zero = {0.f,0.f,0.f,0.f};

  // ---- phase 0: load seq chunk (16x512 f32), reductions for rs/lr/mom/dec
  // f = tid + 256*it -> token c = f>>7 (threads 0..127: c=2it, 128..255: c=2it+1),
  // float4 column k4 = f&127 (same for all it on a given thread).
  const float4* sb = (const float4*)(seq + ((size_t)(b*SX + t*CHX))*DIMX);
  float4 q[8];
  #pragma unroll
  for (int it=0; it<8; it++) q[it] = sb[tid + 256*it];
  int k4 = tid & 127; int d0 = k4*4;
  float4 sc4 = *(const float4*)(scale + d0);
  float wsv[4], wmv[4], wdv[4];
  #pragma unroll
  for (int j=0;j<4;j++){
    wsv[j] = Wstep[(d0+j)*4 + h];
    wmv[j] = Wmom [(d0+j)*4 + h];
    wdv[j] = Wdec [(d0+j)*4 + h];
  }
  #pragma unroll
  for (int it=0; it<8; it++){
    float ssp = q[it].x*q[it].x + q[it].y*q[it].y + q[it].z*q[it].z + q[it].w*q[it].w;
    float xwx = q[it].x*sc4.x, xwy = q[it].y*sc4.y;
    float xwz = q[it].z*sc4.z, xww = q[it].w*sc4.w;
    float lp = xwx*wsv[0] + xwy*wsv[1] + xwz*wsv[2] + xww*wsv[3];
    float pm = xwx*wmv[0] + xwy*wmv[1] + xwz*wmv[2] + xww*wmv[3];
    float pd = xwx*wdv[0] + xwy*wdv[1] + xwz*wdv[2] + xww*wdv[3];
    #pragma unroll
    for (int o=32;o>0;o>>=1){
      ssp += __shfl_down(ssp,o,64); lp += __shfl_down(lp,o,64);
      pm  += __shfl_down(pm,o,64);  pd += __shfl_down(pd,o,64);
    }
    if (lane==0){ red[wv][it][0]=ssp; red[wv][it][1]=lp; red[wv][it][2]=pm; red[wv][it][3]=pd; }
  }
  __syncthreads();
  if (tid < 16){
    int c = tid;
    int w0i = (c & 1) ? 2 : 0;       // even c: waves 0+1, odd c: waves 2+3
    int iti = c >> 1;
    float ssc = red[w0i][iti][0] + red[w0i+1][iti][0];
    float lpc = red[w0i][iti][1] + red[w0i+1][iti][1];
    float pmc = red[w0i][iti][2] + red[w0i+1][iti][2];
    float pdc = red[w0i][iti][3] + red[w0i+1][iti][3];
    float rs = 1.0f / sqrtf(ssc*(1.0f/DIMX) + 1e-6f);
    rs_s[c] = rs;
    lr_s[c] = 0.01f * sigmoidf_(rs*lpc);
    float pmr = rs*pmc, pdr = rs*pdc;
    #pragma unroll
    for (int o=8;o>0;o>>=1){ pmr += __shfl_down(pmr,o,16); pdr += __shfl_down(pdr,o,16); }
    if (c==0){
      momw[bt] = sigmoidf_(pmr*(1.0f/CHX));
      decw[bt] = 1.0f - sigmoidf_(pdr*(1.0f/CHX));
    }
  }
  __syncthreads();
  // ---- pack normalized x as bf16 into xs
  #pragma unroll
  for (int it=0; it<8; it++){
    int f = tid + 256*it;
    int c = f >> 7;
    float rs = rs_s[c];
    uint2 u;
    u.x = pk2(q[it].x*rs*sc4.x, q[it].y*rs*sc4.y);
    u.y = pk2(q[it].z*rs*sc4.z, q[it].w*rs*sc4.w);
    *(uint2*)&xs[c*PADX + k4*4] = u;
  }
  __syncthreads();

  // ---- KV gemm: M=16 (c), N=256 (k|v cols), K=512
  f32x4 kacc[2] = {zero, zero};
  f32x4 vacc[2] = {zero, zero};
  const ushort_t* wkvh = WkvT + (size_t)h*16*256*32;
  for (int kt=0; kt<16; kt++){
    bf16x8 Af = *(const bf16x8*)&xs[nl*PADX + kt*32 + quad*8];
    #pragma unroll
    for (int s=0; s<2; s++){
      int ktile = 2*wv + s;
      bf16x8 Bk = *(const bf16x8*)&wkvh[((size_t)kt*256 + (ktile*16+nl))*32 + quad*8];
      kacc[s] = __builtin_amdgcn_mfma_f32_16x16x32_bf16(Af, Bk, kacc[s], 0,0,0);
      int vtile = 8 + 2*wv + s;
      bf16x8 Bv = *(const bf16x8*)&wkvh[((size_t)kt*256 + (vtile*16+nl))*32 + quad*8];
      vacc[s] = __builtin_amdgcn_mfma_f32_16x16x32_bf16(Af, Bv, vacc[s], 0,0,0);
    }
  }
  #pragma unroll
  for (int s=0;s<2;s++){
    #pragma unroll
    for (int r=0;r<4;r++)
      ks[(quad*4+r)*PADF + 32*wv + 16*s + nl] = f2bf(kacc[s][r]);
  }
  __syncthreads();

  // ---- gemm1: h = k @ w0
  const ushort_t* w0b = w0T + (size_t)bh*16384;
  f32x4 hacc[2] = {zero, zero};
  for (int kt=0; kt<4; kt++){
    bf16x8 Af = *(const bf16x8*)&ks[nl*PADF + kt*32 + quad*8];
    #pragma unroll
    for (int s=0; s<2; s++){
      int n0 = (2*wv+s)*16;
      bf16x8 Bf = *(const bf16x8*)&w0b[(size_t)(n0+nl)*128 + kt*32 + quad*8];
      hacc[s] = __builtin_amdgcn_mfma_f32_16x16x32_bf16(Af, Bf, hacc[s], 0,0,0);
    }
  }
  float sp[2][4];
  #pragma unroll
  for (int s=0;s<2;s++){
    #pragma unroll
    for (int r=0;r<4;r++){
      float hh = hacc[s][r];
      float sg = sigmoidf_(hh);
      float a  = hh*sg;
      sp[s][r] = sg*(1.0f + hh*(1.0f-sg));
      as_[(quad*4+r)*PADF + 32*wv + 16*s + nl] = f2bf(a);
    }
  }
  __syncthreads();

  // ---- gemm2: pred = a @ w1 ; dpred = 2/DH * lr * (pred - v)
  const ushort_t* w1tb = w1T + (size_t)bh*16384;
  f32x4 pacc[2] = {zero, zero};
  for (int kt=0; kt<4; kt++){
    bf16x8 Af = *(const bf16x8*)&as_[nl*PADF + kt*32 + quad*8];
    #pragma unroll
    for (int s=0; s<2; s++){
      int n0 = (2*wv+s)*16;
      bf16x8 Bf = *(const bf16x8*)&w1tb[(size_t)(n0+nl)*128 + kt*32 + quad*8];
      pacc[s] = __builtin_amdgcn_mfma_f32_16x16x32_bf16(Af, Bf, pacc[s], 0,0,0);
    }
  }
  float lrv[4];
  #pragma unroll
  for (int r=0;r<4;r++) lrv[r] = lr_s[quad*4 + r];
  #pragma unroll
  for (int s=0;s<2;s++){
    #pragma unroll
    for (int r=0;r<4;r++){
      float dp = (2.0f/DHX)*lrv[r]*(pacc[s][r] - vacc[s][r]);
      dp_[(quad*4+r)*PADF + 32*wv + 16*s + nl] = f2bf(dp);
    }
  }
  __syncthreads();

  // ---- gemm3: da = dpred @ w1^T ; dh0 = da * silu'(h)
  const ushort_t* w1nb = w1n + (size_t)bh*16384;
  f32x4 dacc[2] = {zero, zero};
  for (int kt=0; kt<4; kt++){
    bf16x8 Af = *(const bf16x8*)&dp_[nl*PADF + kt*32 + quad*8];
    #pragma unroll
    for (int s=0; s<2; s++){
      int n0 = (2*wv+s)*16;
      bf16x8 Bf = *(const bf16x8*)&w1nb[(size_t)(n0+nl)*128 + kt*32 + quad*8];
      dacc[s] = __builtin_amdgcn_mfma_f32_16x16x32_bf16(Af, Bf, dacc[s], 0,0,0);
    }
  }
  #pragma unroll
  for (int s=0;s<2;s++){
    #pragma unroll
    for (int r=0;r<4;r++)
      dh_[(quad*4+r)*PADF + 32*wv + 16*s + nl] = f2bf(dacc[s][r]*sp[s][r]);
  }
  __syncthreads();

  // ---- pack: fac0 row p = {k c0..15 | a c0..15}, fac1 row p = {dh c0..15 | dp c0..15}
  {
    int p = tid & 127, which = tid >> 7;
    const ushort_t* s0 = which ? dh_ : ks;
    const ushort_t* s1 = which ? dp_ : as_;
    ushort_t rowv[32];
    #pragma unroll
    for (int c=0;c<16;c++){ rowv[c] = s0[c*PADF + p]; rowv[16+c] = s1[c*PADF + p]; }
    ushort_t* dst = (which ? fac1 : fac0) + ((size_t)bt*128 + p)*32;
    const uint4* rv = (const uint4*)rowv;
    uint4* dq = (uint4*)dst;
    dq[0]=rv[0]; dq[1]=rv[1]; dq[2]=rv[2]; dq[3]=rv[3];
  }
}

// ---------------- K-scan3: barrier-free, LDS-free MFMA scan ----------------
// 1024 blocks x 64 threads: blk = bh | jb<<3 | ig<<6 | mat<<9 (bh in low bits
// keeps each bh's 2MB fac slice on one XCD's L2). One wave owns one
// (mat, i-tile, j-tile) task for all 128 chunks. Fragments load straight
// global->VGPR (fragment layout == fac row layout); no LDS, no barriers, so
// output stores stream at HBM write BW with no vmcnt(0) drains.
__global__ __launch_bounds__(64) void k_scan3(const ushort_t* __restrict__ fac0,
    const ushort_t* __restrict__ fac1,
    const float* __restrict__ momw, const float* __restrict__ decw,
    float* __restrict__ out){
  int blk = blockIdx.x;
  int bh  = blk & 7;
  int jb  = (blk >> 3) & 7;
  int ig  = (blk >> 6) & 7;
  int mat = blk >> 9;
  int lane = threadIdx.x;
  int quad = lane >> 4, rrow = lane & 15;
  const f32x4 zero = {0.f,0.f,0.f,0.f};
  const bf16x8 fz = {0,0,0,0,0,0,0,0};

  size_t rowbase = (size_t)bh*NCX*128;
  const ushort_t* pa = fac0 + (rowbase + (size_t)(ig*16 + rrow))*32 + mat*16 + quad*8;
  const ushort_t* pb = fac1 + (rowbase + (size_t)(jb*16 + rrow))*32 + mat*16 + quad*8;
  bool act = (quad < 2);   // chunks 16..31 of the K dim are zero padding

  bf16x8 fa0=fz, fb0=fz, fa1=fz, fb1=fz;
  if (act){
    fa0 = *(const bf16x8*)(pa);
    fb0 = *(const bf16x8*)(pb);
    fa1 = *(const bf16x8*)(pa + 4096);
    fb1 = *(const bf16x8*)(pb + 4096);
  }

  f32x4 m_ = zero, u_ = zero;
  size_t obase = ((size_t)(mat*BHX + bh)*NCX)*((size_t)DHX*DHX)
               + (size_t)(ig*16 + quad*4)*DHX + (size_t)(jb*16 + rrow);
  const float* mop = momw + bh*NCX;
  const float* dep = decw + bh*NCX;

  for (int t=0; t<NCX; t+=2){
    bf16x8 na0=fz, nb0=fz, na1=fz, nb1=fz;
    if (act && (t+2 < NCX)){
      na0 = *(const bf16x8*)(pa + (size_t)(t+2)*4096);
      nb0 = *(const bf16x8*)(pb + (size_t)(t+2)*4096);
      na1 = *(const bf16x8*)(pa + (size_t)(t+3)*4096);
      nb1 = *(const bf16x8*)(pb + (size_t)(t+3)*4096);
    }
    float mo = mop[t], de = dep[t];
    f32x4 g = __builtin_amdgcn_mfma_f32_16x16x32_bf16(fa0, fb0, zero, 0,0,0);
    float* ob = out + obase + (size_t)t*(DHX*DHX);
    #pragma unroll
    for (int r=0;r<4;r++){
      m_[r] = mo*m_[r] - g[r];
      u_[r] = de*u_[r] + m_[r];
      ob[(size_t)r*DHX] = u_[r];
    }
    mo = mop[t+1]; de = dep[t+1];
    g = __builtin_amdgcn_mfma_f32_16x16x32_bf16(fa1, fb1, zero, 0,0,0);
    ob += (size_t)DHX*DHX;
    #pragma unroll
    for (int r=0;r<4;r++){
      m_[r] = mo*m_[r] - g[r];
      u_[r] = de*u_[r] + m_[r];
      ob[(size_t)r*DHX] = u_[r];
    }
    fa0=na0; fb0=nb0; fa1=na1; fb1=nb1;
  }
}

extern "C" void kernel_launch(void* const* d_in, const int* in_sizes, int n_in,
                              void* d_out, int out_size, void* d_ws, size_t ws_size,
                              hipStream_t stream) {
  (void)in_sizes; (void)n_in; (void)out_size; (void)ws_size;
  const float* seq   = (const float*)d_in[0];
  const float* scale = (const float*)d_in[1];
  const float* Wkv   = (const float*)d_in[2];
  const float* Wstep = (const float*)d_in[3];
  const float* Wmom  = (const float*)d_in[4];
  const float* Wdec  = (const float*)d_in[5];
  const float* w0    = (const float*)d_in[6];
  const float* w1    = (const float*)d_in[7];
  float* out = (float*)d_out;

  // workspace layout
  ushort_t* fac0 = (ushort_t*)d_ws;              // 4,194,304 ushorts (8 MB)
  ushort_t* fac1 = fac0 + 4194304;               // 4,194,304 ushorts
  ushort_t* WkvT = fac1 + 4194304;               // 524,288 ushorts
  ushort_t* w0T  = WkvT + 524288;                // 131,072 ushorts
  ushort_t* w1T  = w0T + 131072;                 // 131,072 ushorts
  ushort_t* w1n  = w1T + 131072;                 // 131,072 ushorts
  float*    momw = (float*)(w1n + 131072);       // 1,024 floats
  float*    decw = momw + 1024;                  // 1,024 floats

  k_prep<<<dim3(72), dim3(256), 0, stream>>>(Wkv, w0, w1, WkvT, w0T, w1T, w1n);
  k_fused2<<<dim3(BHX*NCX), dim3(256), 0, stream>>>(seq, scale, Wstep, Wmom, Wdec,
      WkvT, w0T, w1T, w1n, fac0, fac1, momw, decw);
  k_scan3<<<dim3(1024), dim3(64), 0, stream>>>(fac0, fac1, momw, decw, out);
}